// Round 1
// baseline (272.965 us; speedup 1.0000x reference)
//
#include <hip/hip_runtime.h>
#include <math.h>

// Problem dims
#define BSZ_ 8
#define LEN_ 8192
#define PP_  128
#define HH_  128
#define NC_  128          // number of scan chunks
#define CT_  64           // chunk length = LEN_/NC_

// Workspace layout (in floats)
#define OFF_PRM 0                                  // 128 * 16 per-p params
#define OFF_W1  2048                               // (128 x 256) = c1[p]*B[p,h,c]  (h-major)
#define OFF_W2  (OFF_W1 + 128*256)                 // (256 x 128) = [Cr; -Ci] stacked (pc-major)
#define OFF_SUM (OFF_W2 + 256*128)                 // chunk summaries: B*NC*256 channels * 2 states
#define OFF_F   (OFF_SUM + BSZ_*NC_*256*2)         // F / Y buffer: (B, L, 256) interleaved (p,comp)
// total floats = OFF_F + BSZ_*LEN_*256 = 591872 + 16777216  (~66.3 MB)

// ---------------------------------------------------------------------------
// Setup: per-p scalars (dt_s, projected A, M entries, M^CT) and W1/W2 weights
// ---------------------------------------------------------------------------
__global__ void k_setup(const float* __restrict__ A_diag,
                        const float* __restrict__ G_diag,
                        const float* __restrict__ dt,
                        const float* __restrict__ B,
                        const float* __restrict__ C,
                        float* __restrict__ ws)
{
    int p = threadIdx.x;              // 128 threads
    float dtv = dt[p];
    float dts = 1.f / (1.f + expf(-dtv));
    float A   = fmaxf(A_diag[p], 0.f);
    float G   = fmaxf(G_diag[p], 0.f);
    float dt2 = fmaxf(dts * dts, 1e-6f);
    float s   = sqrtf(1.f + dts * G);
    float A_low  = (2.f + dts * G - 2.f * s) / dt2;
    float A_high = (2.f + dts * G + 2.f * s) / dt2;
    float Af = A_low + fmaxf(A - A_low, 0.f) - fmaxf(A - A_high, 0.f);
    float S   = 1.f + dts * G;
    float M11 = 1.f / S;
    float M12 = -(dts / S) * Af;
    float M21 = dts / S;
    float M22 = 1.f - (dts * dts / S) * Af;

    // MT = M^CT_ via 6 squarings (CT_ = 64); spectral radius <= 1 (projection), stable.
    float t11 = M11, t12 = M12, t21 = M21, t22 = M22;
#pragma unroll
    for (int i = 0; i < 6; ++i) {
        float n11 = t11 * t11 + t12 * t21;
        float n12 = t11 * t12 + t12 * t22;
        float n21 = t21 * t11 + t22 * t21;
        float n22 = t21 * t12 + t22 * t22;
        t11 = n11; t12 = n12; t21 = n21; t22 = n22;
    }
    float* prm = ws + OFF_PRM + p * 16;
    prm[0] = M11; prm[1] = M12; prm[2] = M21; prm[3] = M22; prm[4] = dts;
    prm[5] = t11; prm[6] = t12; prm[7] = t21; prm[8] = t22;

    float c1 = dts / S;
    float* W1 = ws + OFF_W1;
    float* W2 = ws + OFF_W2;
    for (int h = 0; h < 128; ++h) {
        // W1[h][2p+c] = c1 * B[p,h,c]   (B layout: (p*128+h)*2+c)
        W1[h * 256 + 2 * p]     = c1 * B[(p * 128 + h) * 2 + 0];
        W1[h * 256 + 2 * p + 1] = c1 * B[(p * 128 + h) * 2 + 1];
        // W2[2p][h] = Cr[h,p]; W2[2p+1][h] = -Ci[h,p]  (C layout: (h*128+p)*2+c)
        W2[(2 * p) * 128 + h]     =  C[(h * 128 + p) * 2 + 0];
        W2[(2 * p + 1) * 128 + h] = -C[(h * 128 + p) * 2 + 1];
    }
}

// ---------------------------------------------------------------------------
// GEMM1: F (M x 256) = X (M x 128) * W1 (128 x 256).  64x64 tiles, 4x4/thread.
// ---------------------------------------------------------------------------
__global__ __launch_bounds__(256) void k_gemm1(const float* __restrict__ X,
                                               float* __restrict__ ws)
{
    __shared__ float Xs[64][68];
    __shared__ float Ws[64][64];
    const float* W = ws + OFF_W1;
    float* F = ws + OFF_F;
    int tid = threadIdx.x;
    int tx = tid & 15, ty = tid >> 4;
    size_t row0 = (size_t)blockIdx.x * 64;
    int col0 = blockIdx.y * 64;
    float acc[4][4] = {};

    for (int kt = 0; kt < 2; ++kt) {
        int k0 = kt * 64;
#pragma unroll
        for (int i = 0; i < 4; ++i) {
            int rr = ty + i * 16;
            float4 v = *(const float4*)(X + (row0 + rr) * 128 + k0 + tx * 4);
            *(float4*)&Xs[rr][tx * 4] = v;
            float4 w = *(const float4*)(W + (size_t)(k0 + rr) * 256 + col0 + tx * 4);
            *(float4*)&Ws[rr][tx * 4] = w;
        }
        __syncthreads();
#pragma unroll 8
        for (int k = 0; k < 64; ++k) {
            float av[4];
#pragma unroll
            for (int i = 0; i < 4; ++i) av[i] = Xs[ty * 4 + i][k];
            float4 bv = *(const float4*)&Ws[k][tx * 4];
            float bvv[4] = {bv.x, bv.y, bv.z, bv.w};
#pragma unroll
            for (int i = 0; i < 4; ++i)
#pragma unroll
                for (int j = 0; j < 4; ++j)
                    acc[i][j] = fmaf(av[i], bvv[j], acc[i][j]);
        }
        __syncthreads();
    }
#pragma unroll
    for (int i = 0; i < 4; ++i) {
        float4 o = make_float4(acc[i][0], acc[i][1], acc[i][2], acc[i][3]);
        *(float4*)(F + (row0 + ty * 4 + i) * 256 + col0 + tx * 4) = o;
    }
}

// ---------------------------------------------------------------------------
// Scan pass 1: per-chunk local final states (zero init)
// ---------------------------------------------------------------------------
__global__ __launch_bounds__(256) void k_scan1(float* __restrict__ ws)
{
    const float* F = ws + OFF_F;
    float* Ssum = ws + OFF_SUM;
    int tid = threadIdx.x;                 // channel pc = 2p+comp
    int b = blockIdx.x >> 7;               // / NC_
    int c = blockIdx.x & (NC_ - 1);
    int p = tid >> 1;
    const float* prm = ws + OFF_PRM + p * 16;
    float M11 = prm[0], M12 = prm[1], M21 = prm[2], M22 = prm[3], dts = prm[4];
    const float* Fp = F + ((size_t)b * LEN_ + (size_t)c * CT_) * 256 + tid;
    float h1 = 0.f, h2 = 0.f;
#pragma unroll 4
    for (int t = 0; t < CT_; ++t) {
        float u1 = Fp[(size_t)t * 256];
        float nh1 = fmaf(M11, h1, fmaf(M12, h2, u1));
        float nh2 = fmaf(M21, h1, fmaf(M22, h2, dts * u1));
        h1 = nh1; h2 = nh2;
    }
    size_t si = (((size_t)b * NC_ + c) * 256 + tid) * 2;
    Ssum[si] = h1; Ssum[si + 1] = h2;
}

// ---------------------------------------------------------------------------
// Scan pass 2: sequential combine of chunk summaries; overwrite with prefixes
// ---------------------------------------------------------------------------
__global__ __launch_bounds__(256) void k_scan2(float* __restrict__ ws)
{
    float* Ssum = ws + OFF_SUM;
    int b = blockIdx.x;                    // 8 blocks
    int tid = threadIdx.x;                 // channel
    int p = tid >> 1;
    const float* prm = ws + OFF_PRM + p * 16;
    float T11 = prm[5], T12 = prm[6], T21 = prm[7], T22 = prm[8];
    float e1 = 0.f, e2 = 0.f;
    float* Sb = Ssum + ((size_t)b * NC_ * 256 + tid) * 2;
#pragma unroll 4
    for (int j = 0; j < NC_; ++j) {
        float l1 = Sb[(size_t)j * 512];
        float l2 = Sb[(size_t)j * 512 + 1];
        Sb[(size_t)j * 512]     = e1;      // prefix (state before chunk j)
        Sb[(size_t)j * 512 + 1] = e2;
        float n1 = fmaf(T11, e1, fmaf(T12, e2, l1));
        float n2 = fmaf(T21, e1, fmaf(T22, e2, l2));
        e1 = n1; e2 = n2;
    }
}

// ---------------------------------------------------------------------------
// Scan pass 3: replay with correct prefix; write ys (=h2) in place over F
// ---------------------------------------------------------------------------
__global__ __launch_bounds__(256) void k_scan3(float* __restrict__ ws)
{
    float* F = ws + OFF_F;
    const float* Ssum = ws + OFF_SUM;
    int tid = threadIdx.x;
    int b = blockIdx.x >> 7;
    int c = blockIdx.x & (NC_ - 1);
    int p = tid >> 1;
    const float* prm = ws + OFF_PRM + p * 16;
    float M11 = prm[0], M12 = prm[1], M21 = prm[2], M22 = prm[3], dts = prm[4];
    size_t si = (((size_t)b * NC_ + c) * 256 + tid) * 2;
    float h1 = Ssum[si], h2 = Ssum[si + 1];
    float* Fp = F + ((size_t)b * LEN_ + (size_t)c * CT_) * 256 + tid;
#pragma unroll 4
    for (int t = 0; t < CT_; ++t) {
        float u1 = Fp[(size_t)t * 256];
        float nh1 = fmaf(M11, h1, fmaf(M12, h2, u1));
        float nh2 = fmaf(M21, h1, fmaf(M22, h2, dts * u1));
        h1 = nh1; h2 = nh2;
        Fp[(size_t)t * 256] = h2;          // ys, in place
    }
}

// ---------------------------------------------------------------------------
// GEMM2: out (M x 128) = Y (M x 256) * W2 (256 x 128) + D .* x
// ---------------------------------------------------------------------------
__global__ __launch_bounds__(256) void k_gemm2(const float* __restrict__ x,
                                               const float* __restrict__ Dv,
                                               float* __restrict__ ws,
                                               float* __restrict__ out)
{
    __shared__ float Xs[64][68];
    __shared__ float Ws[64][64];
    const float* Y = ws + OFF_F;
    const float* W = ws + OFF_W2;
    int tid = threadIdx.x;
    int tx = tid & 15, ty = tid >> 4;
    size_t row0 = (size_t)blockIdx.x * 64;
    int col0 = blockIdx.y * 64;
    float acc[4][4] = {};

    for (int kt = 0; kt < 4; ++kt) {
        int k0 = kt * 64;
#pragma unroll
        for (int i = 0; i < 4; ++i) {
            int rr = ty + i * 16;
            float4 v = *(const float4*)(Y + (row0 + rr) * 256 + k0 + tx * 4);
            *(float4*)&Xs[rr][tx * 4] = v;
            float4 w = *(const float4*)(W + (size_t)(k0 + rr) * 128 + col0 + tx * 4);
            *(float4*)&Ws[rr][tx * 4] = w;
        }
        __syncthreads();
#pragma unroll 8
        for (int k = 0; k < 64; ++k) {
            float av[4];
#pragma unroll
            for (int i = 0; i < 4; ++i) av[i] = Xs[ty * 4 + i][k];
            float4 bv = *(const float4*)&Ws[k][tx * 4];
            float bvv[4] = {bv.x, bv.y, bv.z, bv.w};
#pragma unroll
            for (int i = 0; i < 4; ++i)
#pragma unroll
                for (int j = 0; j < 4; ++j)
                    acc[i][j] = fmaf(av[i], bvv[j], acc[i][j]);
        }
        __syncthreads();
    }
    float4 dv = *(const float4*)(Dv + col0 + tx * 4);
#pragma unroll
    for (int i = 0; i < 4; ++i) {
        size_t r = row0 + ty * 4 + i;
        float4 xv = *(const float4*)(x + r * 128 + col0 + tx * 4);
        float4 o;
        o.x = fmaf(dv.x, xv.x, acc[i][0]);
        o.y = fmaf(dv.y, xv.y, acc[i][1]);
        o.z = fmaf(dv.z, xv.z, acc[i][2]);
        o.w = fmaf(dv.w, xv.w, acc[i][3]);
        *(float4*)(out + r * 128 + col0 + tx * 4) = o;
    }
}

// ---------------------------------------------------------------------------
extern "C" void kernel_launch(void* const* d_in, const int* in_sizes, int n_in,
                              void* d_out, int out_size, void* d_ws, size_t ws_size,
                              hipStream_t stream) {
    const float* x      = (const float*)d_in[0];
    const float* A_diag = (const float*)d_in[1];
    const float* G_diag = (const float*)d_in[2];
    const float* dt     = (const float*)d_in[3];
    const float* B      = (const float*)d_in[4];
    const float* C      = (const float*)d_in[5];
    const float* Dv     = (const float*)d_in[6];
    float* out = (float*)d_out;
    float* ws  = (float*)d_ws;
    // required ws: (OFF_F + BSZ_*LEN_*256)*4 bytes ~= 66.3 MB

    k_setup<<<1, 128, 0, stream>>>(A_diag, G_diag, dt, B, C, ws);
    k_gemm1<<<dim3((BSZ_ * LEN_) / 64, 4), 256, 0, stream>>>(x, ws);
    k_scan1<<<BSZ_ * NC_, 256, 0, stream>>>(ws);
    k_scan2<<<BSZ_, 256, 0, stream>>>(ws);
    k_scan3<<<BSZ_ * NC_, 256, 0, stream>>>(ws);
    k_gemm2<<<dim3((BSZ_ * LEN_) / 64, 2), 256, 0, stream>>>(x, Dv, ws, out);
}

// Round 2
// 187.299 us; speedup vs baseline: 1.4574x; 1.4574x over previous
//
#include <hip/hip_runtime.h>
#include <math.h>

// Problem dims
#define BSZ_ 8
#define LEN_ 8192
#define NC_  128          // scan chunks per sequence
#define CT_  64           // chunk length

typedef __attribute__((ext_vector_type(8))) short bf16x8;
typedef __attribute__((ext_vector_type(4))) float f32x4;

// Workspace layout (float offsets)
#define OFF_PRM 0                                   // 128*16 per-p scalars
#define OFF_W1T 2048                                // bf16 [256][128]  (W1^T: [pc][h])
#define OFF_W2T (OFF_W1T + 16384)                   // bf16 [128][256]  (W2^T: [h][pc])
#define OFF_SUM (OFF_W2T + 16384)                   // f32 chunk summaries [8][128][256][2]
#define OFF_F   (OFF_SUM + BSZ_*NC_*256*2)          // f32 F buffer [8][8192][256]
// total = 17,336,320 floats = 69.3 MB (<= previous 69.5 MB)

__device__ __forceinline__ unsigned short f2bf(float f) {
    unsigned u = __builtin_bit_cast(unsigned, f);
    u += 0x7fffu + ((u >> 16) & 1u);               // round-to-nearest-even
    return (unsigned short)(u >> 16);
}

// ---------------------------------------------------------------------------
// Setup: per-p scalars (M, dts, M^64) + bf16 transposed weights W1T, W2T
// ---------------------------------------------------------------------------
__global__ void k_setup(const float* __restrict__ A_diag,
                        const float* __restrict__ G_diag,
                        const float* __restrict__ dt,
                        const float* __restrict__ B,
                        const float* __restrict__ C,
                        float* __restrict__ ws)
{
    int p = threadIdx.x;              // 128 threads
    float dtv = dt[p];
    float dts = 1.f / (1.f + expf(-dtv));
    float A   = fmaxf(A_diag[p], 0.f);
    float G   = fmaxf(G_diag[p], 0.f);
    float dt2 = fmaxf(dts * dts, 1e-6f);
    float s   = sqrtf(1.f + dts * G);
    float A_low  = (2.f + dts * G - 2.f * s) / dt2;
    float A_high = (2.f + dts * G + 2.f * s) / dt2;
    float Af = A_low + fmaxf(A - A_low, 0.f) - fmaxf(A - A_high, 0.f);
    float S   = 1.f + dts * G;
    float M11 = 1.f / S;
    float M12 = -(dts / S) * Af;
    float M21 = dts / S;
    float M22 = 1.f - (dts * dts / S) * Af;

    // M^64 via 6 squarings (spectral radius <= 1 by projection)
    float t11 = M11, t12 = M12, t21 = M21, t22 = M22;
#pragma unroll
    for (int i = 0; i < 6; ++i) {
        float n11 = t11 * t11 + t12 * t21;
        float n12 = t11 * t12 + t12 * t22;
        float n21 = t21 * t11 + t22 * t21;
        float n22 = t21 * t12 + t22 * t22;
        t11 = n11; t12 = n12; t21 = n21; t22 = n22;
    }
    float* prm = ws + OFF_PRM + p * 16;
    prm[0] = M11; prm[1] = M12; prm[2] = M21; prm[3] = M22; prm[4] = dts;
    prm[5] = t11; prm[6] = t12; prm[7] = t21; prm[8] = t22;

    float c1 = dts / S;
    unsigned short* W1T = (unsigned short*)(ws + OFF_W1T);   // [pc][h]
    unsigned short* W2T = (unsigned short*)(ws + OFF_W2T);   // [h][pc]
    for (int h = 0; h < 128; ++h) {
        W1T[(2 * p)     * 128 + h] = f2bf(c1 * B[(p * 128 + h) * 2 + 0]);
        W1T[(2 * p + 1) * 128 + h] = f2bf(c1 * B[(p * 128 + h) * 2 + 1]);
        W2T[h * 256 + 2 * p]       = f2bf( C[(h * 128 + p) * 2 + 0]);
        W2T[h * 256 + 2 * p + 1]   = f2bf(-C[(h * 128 + p) * 2 + 1]);
    }
}

// ---------------------------------------------------------------------------
// Fused 1: GEMM1 (MFMA bf16, 64x256 tile = one chunk) + local scan (pass 1)
// grid = 1024 blocks (b,c), 256 threads
// ---------------------------------------------------------------------------
__global__ __launch_bounds__(256) void k_fuse1(const float* __restrict__ X,
                                               float* __restrict__ ws)
{
    __shared__ unsigned short xs[64][136];     // x tile bf16  [m=l][k=h]
    __shared__ unsigned short w1t[256][136];   // W1^T bf16    [n=pc][k=h]
    __shared__ float fl[64][260];              // F tile fp32  [l][pc]

    int tid = threadIdx.x;
    int b = blockIdx.x >> 7;
    int c = blockIdx.x & 127;
    size_t row0 = (size_t)b * LEN_ + (size_t)c * CT_;

    // ---- stage x (fp32 -> bf16) and W1T into LDS ----
    {
        int r = tid >> 4, cl = (tid & 15) * 8;
#pragma unroll
        for (int i = 0; i < 4; ++i) {
            int rr = r + i * 16;
            const float* src = X + (row0 + rr) * 128 + cl;
            float4 v0 = *(const float4*)src;
            float4 v1 = *(const float4*)(src + 4);
            unsigned short* dst = &xs[rr][cl];
            dst[0] = f2bf(v0.x); dst[1] = f2bf(v0.y); dst[2] = f2bf(v0.z); dst[3] = f2bf(v0.w);
            dst[4] = f2bf(v1.x); dst[5] = f2bf(v1.y); dst[6] = f2bf(v1.z); dst[7] = f2bf(v1.w);
        }
        const unsigned short* W1T = (const unsigned short*)(ws + OFF_W1T);
#pragma unroll
        for (int i = 0; i < 16; ++i) {
            int rr = r + i * 16;
            *(bf16x8*)&w1t[rr][cl] = *(const bf16x8*)(W1T + rr * 128 + cl);
        }
    }
    __syncthreads();

    // ---- MFMA GEMM1: wave w covers cols [w*64, w*64+64) ----
    int wv = tid >> 6, lane = tid & 63;
    int l15 = lane & 15, quad = lane >> 4;
    int nbase = wv * 64;
    f32x4 acc[4][4] = {};
#pragma unroll
    for (int kk = 0; kk < 4; ++kk) {
        int k0 = kk * 32 + quad * 8;
        bf16x8 af[4], bg[4];
#pragma unroll
        for (int mi = 0; mi < 4; ++mi) af[mi] = *(const bf16x8*)&xs[mi * 16 + l15][k0];
#pragma unroll
        for (int nj = 0; nj < 4; ++nj) bg[nj] = *(const bf16x8*)&w1t[nbase + nj * 16 + l15][k0];
#pragma unroll
        for (int mi = 0; mi < 4; ++mi)
#pragma unroll
            for (int nj = 0; nj < 4; ++nj)
                acc[mi][nj] = __builtin_amdgcn_mfma_f32_16x16x32_bf16(af[mi], bg[nj], acc[mi][nj], 0, 0, 0);
    }
    // C/D layout: col = lane&15, row = quad*4 + reg
#pragma unroll
    for (int mi = 0; mi < 4; ++mi)
#pragma unroll
        for (int nj = 0; nj < 4; ++nj)
#pragma unroll
            for (int r = 0; r < 4; ++r)
                fl[mi * 16 + quad * 4 + r][nbase + nj * 16 + l15] = acc[mi][nj][r];
    __syncthreads();

    // ---- local scan over chunk (zero init), channel = tid ----
    {
        const float* prm = ws + OFF_PRM + (tid >> 1) * 16;
        float M11 = prm[0], M12 = prm[1], M21 = prm[2], M22 = prm[3], dts = prm[4];
        float h1 = 0.f, h2 = 0.f;
#pragma unroll 8
        for (int t = 0; t < CT_; ++t) {
            float u = fl[t][tid];
            float n1 = fmaf(M11, h1, fmaf(M12, h2, u));
            float n2 = fmaf(M21, h1, fmaf(M22, h2, dts * u));
            h1 = n1; h2 = n2;
        }
        float* Ssum = ws + OFF_SUM;
        size_t si = (((size_t)b * NC_ + c) * 256 + tid) * 2;
        Ssum[si] = h1; Ssum[si + 1] = h2;
    }

    // ---- write F tile to global (coalesced float4) ----
    {
        float* F = ws + OFF_F;
        int cl4 = tid & 63;
        int r = tid >> 6;
#pragma unroll
        for (int i = 0; i < 16; ++i) {
            int rr = r + i * 4;
            *(float4*)(F + (row0 + rr) * 256 + cl4 * 4) = *(const float4*)&fl[rr][cl4 * 4];
        }
    }
}

// ---------------------------------------------------------------------------
// Pass 2: sequential combine of chunk summaries -> prefixes (8 blocks)
// ---------------------------------------------------------------------------
__global__ __launch_bounds__(256) void k_scan2(float* __restrict__ ws)
{
    float* Ssum = ws + OFF_SUM;
    int b = blockIdx.x;
    int tid = threadIdx.x;
    const float* prm = ws + OFF_PRM + (tid >> 1) * 16;
    float T11 = prm[5], T12 = prm[6], T21 = prm[7], T22 = prm[8];
    float e1 = 0.f, e2 = 0.f;
    float* Sb = Ssum + ((size_t)b * NC_ * 256 + tid) * 2;
#pragma unroll 4
    for (int j = 0; j < NC_; ++j) {
        float l1 = Sb[(size_t)j * 512];
        float l2 = Sb[(size_t)j * 512 + 1];
        Sb[(size_t)j * 512]     = e1;
        Sb[(size_t)j * 512 + 1] = e2;
        float n1 = fmaf(T11, e1, fmaf(T12, e2, l1));
        float n2 = fmaf(T21, e1, fmaf(T22, e2, l2));
        e1 = n1; e2 = n2;
    }
}

// ---------------------------------------------------------------------------
// Fused 2: replay scan with prefix (F from global, ys -> LDS bf16)
//          + GEMM2 (MFMA bf16) + D.*x epilogue
// grid = 1024 blocks (b,c), 256 threads
// ---------------------------------------------------------------------------
__global__ __launch_bounds__(256) void k_fuse2(const float* __restrict__ X,
                                               const float* __restrict__ Dv,
                                               float* __restrict__ ws,
                                               float* __restrict__ out)
{
    __shared__ unsigned short ysb[64][264];    // ys bf16  [m=l][k=pc]
    __shared__ unsigned short w2t[128][264];   // W2^T bf16 [n=h][k=pc]

    int tid = threadIdx.x;
    int b = blockIdx.x >> 7;
    int c = blockIdx.x & 127;
    size_t row0 = (size_t)b * LEN_ + (size_t)c * CT_;

    // ---- stage W2T ----
    {
        int r = tid >> 4, cl = (tid & 15) * 16;
        const unsigned short* W2T = (const unsigned short*)(ws + OFF_W2T);
#pragma unroll
        for (int i = 0; i < 8; ++i) {
            int rr = r + i * 16;
            const unsigned short* src = W2T + rr * 256 + cl;
            *(bf16x8*)&w2t[rr][cl]     = *(const bf16x8*)src;
            *(bf16x8*)&w2t[rr][cl + 8] = *(const bf16x8*)(src + 8);
        }
    }

    // ---- replay scan: channel = tid, F read coalesced from global ----
    {
        const float* prm = ws + OFF_PRM + (tid >> 1) * 16;
        float M11 = prm[0], M12 = prm[1], M21 = prm[2], M22 = prm[3], dts = prm[4];
        const float* Ssum = ws + OFF_SUM;
        size_t si = (((size_t)b * NC_ + c) * 256 + tid) * 2;
        float h1 = Ssum[si], h2 = Ssum[si + 1];
        const float* Fp = ws + OFF_F + row0 * 256 + tid;
#pragma unroll 8
        for (int t = 0; t < CT_; ++t) {
            float u = Fp[(size_t)t * 256];
            float n1 = fmaf(M11, h1, fmaf(M12, h2, u));
            float n2 = fmaf(M21, h1, fmaf(M22, h2, dts * u));
            h1 = n1; h2 = n2;
            ysb[t][tid] = f2bf(h2);
        }
    }
    __syncthreads();

    // ---- MFMA GEMM2: wave covers m-rows (wv&1)*32.., n-cols (wv>>1)*64.. ----
    int wv = tid >> 6, lane = tid & 63;
    int l15 = lane & 15, quad = lane >> 4;
    int mrow = (wv & 1) * 32, ncol = (wv >> 1) * 64;
    f32x4 acc[2][4] = {};
#pragma unroll
    for (int kk = 0; kk < 8; ++kk) {
        int k0 = kk * 32 + quad * 8;
        bf16x8 af[2], bg[4];
#pragma unroll
        for (int mi = 0; mi < 2; ++mi) af[mi] = *(const bf16x8*)&ysb[mrow + mi * 16 + l15][k0];
#pragma unroll
        for (int nj = 0; nj < 4; ++nj) bg[nj] = *(const bf16x8*)&w2t[ncol + nj * 16 + l15][k0];
#pragma unroll
        for (int mi = 0; mi < 2; ++mi)
#pragma unroll
            for (int nj = 0; nj < 4; ++nj)
                acc[mi][nj] = __builtin_amdgcn_mfma_f32_16x16x32_bf16(af[mi], bg[nj], acc[mi][nj], 0, 0, 0);
    }

    // ---- epilogue: out = acc + D .* x (fp32 exact) ----
#pragma unroll
    for (int mi = 0; mi < 2; ++mi)
#pragma unroll
        for (int nj = 0; nj < 4; ++nj) {
            int col = ncol + nj * 16 + l15;
            float d = Dv[col];
#pragma unroll
            for (int r = 0; r < 4; ++r) {
                size_t gr = row0 + mrow + mi * 16 + quad * 4 + r;
                float xv = X[gr * 128 + col];
                out[gr * 128 + col] = fmaf(d, xv, acc[mi][nj][r]);
            }
        }
}

// ---------------------------------------------------------------------------
extern "C" void kernel_launch(void* const* d_in, const int* in_sizes, int n_in,
                              void* d_out, int out_size, void* d_ws, size_t ws_size,
                              hipStream_t stream) {
    const float* x      = (const float*)d_in[0];
    const float* A_diag = (const float*)d_in[1];
    const float* G_diag = (const float*)d_in[2];
    const float* dt     = (const float*)d_in[3];
    const float* B      = (const float*)d_in[4];
    const float* C      = (const float*)d_in[5];
    const float* Dv     = (const float*)d_in[6];
    float* out = (float*)d_out;
    float* ws  = (float*)d_ws;

    k_setup<<<1, 128, 0, stream>>>(A_diag, G_diag, dt, B, C, ws);
    k_fuse1<<<BSZ_ * NC_, 256, 0, stream>>>(x, ws);
    k_scan2<<<BSZ_, 256, 0, stream>>>(ws);
    k_fuse2<<<BSZ_ * NC_, 256, 0, stream>>>(x, Dv, ws, out);
}

// Round 5
// 151.508 us; speedup vs baseline: 1.8017x; 1.2362x over previous
//
#include <hip/hip_runtime.h>
#include <math.h>

// Problem dims
#define BSZ_ 8
#define LEN_ 8192
#define NC_  128          // scan chunks per sequence
#define CT_  64           // chunk length

typedef __attribute__((ext_vector_type(8))) short bf16x8;
typedef __attribute__((ext_vector_type(4))) float f32x4;

// Workspace layout (float offsets).  Total ~2.24 MB: L2-resident
#define OFF_PRM 0                                   // 128*16 per-p scalars
#define OFF_W1T 2048                                // bf16 [256][128]  (W1^T: [pc][h])
#define OFF_W2T (OFF_W1T + 16384)                   // bf16 [128][256]  (W2^T: [h][pc])
#define OFF_SUM (OFF_W2T + 16384)                   // f32 chunk summaries [8][128][256][2]

__device__ __forceinline__ unsigned short f2bf(float f) {
    unsigned u = __builtin_bit_cast(unsigned, f);
    u += 0x7fffu + ((u >> 16) & 1u);               // round-to-nearest-even
    return (unsigned short)(u >> 16);
}

// ---------------------------------------------------------------------------
// Setup: parallel weight conversion (1 elem/thread, coalesced) + prm in block 0
// grid = 128 x 256
// ---------------------------------------------------------------------------
__global__ __launch_bounds__(256) void k_setup(const float* __restrict__ A_diag,
                                               const float* __restrict__ G_diag,
                                               const float* __restrict__ dt,
                                               const float* __restrict__ B,
                                               const float* __restrict__ C,
                                               float* __restrict__ ws)
{
    int i = blockIdx.x * 256 + threadIdx.x;        // 0..32767
    // W1T[pc][h] = c1[p] * B[p,h,c]
    {
        int pc = i >> 7, h = i & 127;
        int p = pc >> 1, cc = pc & 1;
        float dts = 1.f / (1.f + expf(-dt[p]));
        float G = fmaxf(G_diag[p], 0.f);
        float c1 = dts / (1.f + dts * G);
        ((unsigned short*)(ws + OFF_W1T))[i] = f2bf(c1 * B[p * 256 + h * 2 + cc]);
    }
    // W2T[h][pc] = +Cr / -Ci ; C layout is exactly linear in i
    {
        float v = C[i];
        ((unsigned short*)(ws + OFF_W2T))[i] = f2bf((i & 1) ? -v : v);
    }
    if (blockIdx.x == 0 && threadIdx.x < 128) {
        int p = threadIdx.x;
        float dtv = dt[p];
        float dts = 1.f / (1.f + expf(-dtv));
        float A   = fmaxf(A_diag[p], 0.f);
        float G   = fmaxf(G_diag[p], 0.f);
        float dt2 = fmaxf(dts * dts, 1e-6f);
        float s   = sqrtf(1.f + dts * G);
        float A_low  = (2.f + dts * G - 2.f * s) / dt2;
        float A_high = (2.f + dts * G + 2.f * s) / dt2;
        float Af = A_low + fmaxf(A - A_low, 0.f) - fmaxf(A - A_high, 0.f);
        float S   = 1.f + dts * G;
        float M11 = 1.f / S;
        float M12 = -(dts / S) * Af;
        float M21 = dts / S;
        float M22 = 1.f - (dts * dts / S) * Af;
        float t11 = M11, t12 = M12, t21 = M21, t22 = M22;
#pragma unroll
        for (int it = 0; it < 6; ++it) {           // M^64
            float n11 = t11 * t11 + t12 * t21;
            float n12 = t11 * t12 + t12 * t22;
            float n21 = t21 * t11 + t22 * t21;
            float n22 = t21 * t12 + t22 * t22;
            t11 = n11; t12 = n12; t21 = n21; t22 = n22;
        }
        float* prm = ws + OFF_PRM + p * 16;
        prm[0] = M11; prm[1] = M12; prm[2] = M21; prm[3] = M22; prm[4] = dts;
        prm[5] = t11; prm[6] = t12; prm[7] = t21; prm[8] = t22;
    }
}

// ---------------------------------------------------------------------------
// Shared device pieces
// ---------------------------------------------------------------------------
__device__ __forceinline__ void stage_x(const float* __restrict__ X, size_t row0,
                                        int tid, unsigned short (*xs)[136])
{
    int r = tid >> 4, cl = (tid & 15) * 8;
#pragma unroll
    for (int i = 0; i < 4; ++i) {
        int rr = r + i * 16;
        const float* src = X + (row0 + rr) * 128 + cl;
        float4 v0 = *(const float4*)src;
        float4 v1 = *(const float4*)(src + 4);
        unsigned short* dst = &xs[rr][cl];
        dst[0] = f2bf(v0.x); dst[1] = f2bf(v0.y); dst[2] = f2bf(v0.z); dst[3] = f2bf(v0.w);
        dst[4] = f2bf(v1.x); dst[5] = f2bf(v1.y); dst[6] = f2bf(v1.z); dst[7] = f2bf(v1.w);
    }
}

// GEMM1 64x256x128: A = xs (LDS), B-frags straight from global W1T (L2-hot)
__device__ __forceinline__ void gemm1_acc(const unsigned short (*xs)[136],
                                          const unsigned short* __restrict__ W1T,
                                          int wv, int lane, f32x4 acc[4][4])
{
    int l15 = lane & 15, quad = lane >> 4;
    int nbase = wv * 64;
#pragma unroll
    for (int kk = 0; kk < 4; ++kk) {
        int k0 = kk * 32 + quad * 8;
        bf16x8 af[4], bg[4];
#pragma unroll
        for (int mi = 0; mi < 4; ++mi) af[mi] = *(const bf16x8*)&xs[mi * 16 + l15][k0];
#pragma unroll
        for (int nj = 0; nj < 4; ++nj)
            bg[nj] = *(const bf16x8*)(W1T + (size_t)(nbase + nj * 16 + l15) * 128 + k0);
#pragma unroll
        for (int mi = 0; mi < 4; ++mi)
#pragma unroll
            for (int nj = 0; nj < 4; ++nj)
                acc[mi][nj] = __builtin_amdgcn_mfma_f32_16x16x32_bf16(af[mi], bg[nj], acc[mi][nj], 0, 0, 0);
    }
}

// ---------------------------------------------------------------------------
// Fused 1: GEMM1 + local chunk scan (fp32) -> chunk summaries.
// grid = 1024 x 256.  LDS = 64*258*4 = 64.5 KB (xs aliased inside) -> 2 blk/CU
// ---------------------------------------------------------------------------
__global__ __launch_bounds__(256) void k_fuse1(const float* __restrict__ X,
                                               float* __restrict__ ws)
{
    __shared__ __align__(16) char smem[64 * 258 * 4];
    unsigned short (*xs)[136] = (unsigned short (*)[136])smem;  // alias (dead after GEMM1)
    float (*fl)[258] = (float (*)[258])smem;                    // fp32 F tile

    int tid = threadIdx.x;
    int b = blockIdx.x >> 7, c = blockIdx.x & 127;
    size_t row0 = (size_t)b * LEN_ + (size_t)c * CT_;

    stage_x(X, row0, tid, xs);
    __syncthreads();

    int wv = tid >> 6, lane = tid & 63;
    int l15 = lane & 15, quad = lane >> 4, nbase = wv * 64;
    f32x4 acc[4][4] = {};
    gemm1_acc(xs, (const unsigned short*)(ws + OFF_W1T), wv, lane, acc);
    __syncthreads();            // xs fully consumed; fl may now overwrite it

#pragma unroll
    for (int mi = 0; mi < 4; ++mi)
#pragma unroll
        for (int nj = 0; nj < 4; ++nj)
#pragma unroll
            for (int r = 0; r < 4; ++r)
                fl[mi * 16 + quad * 4 + r][nbase + nj * 16 + l15] = acc[mi][nj][r];
    __syncthreads();

    // local scan over chunk (zero init), channel = tid — fp32 throughout
    const float* prm = ws + OFF_PRM + (tid >> 1) * 16;
    float M11 = prm[0], M12 = prm[1], M21 = prm[2], M22 = prm[3], dts = prm[4];
    float h1 = 0.f, h2 = 0.f;
#pragma unroll 8
    for (int t = 0; t < CT_; ++t) {
        float u = fl[t][tid];
        float n1 = fmaf(M11, h1, fmaf(M12, h2, u));
        float n2 = fmaf(M21, h1, fmaf(M22, h2, dts * u));
        h1 = n1; h2 = n2;
    }
    *(float2*)(ws + OFF_SUM + (((size_t)b * NC_ + c) * 256 + tid) * 2) = make_float2(h1, h2);
}

// ---------------------------------------------------------------------------
// Pass 2: sequential combine of chunk summaries -> prefixes.  grid = 32 x 64
// ---------------------------------------------------------------------------
__global__ __launch_bounds__(64) void k_scan2(float* __restrict__ ws)
{
    int b = blockIdx.x >> 2, cg = blockIdx.x & 3;
    int ch = cg * 64 + threadIdx.x;
    const float* prm = ws + OFF_PRM + (ch >> 1) * 16;
    float T11 = prm[5], T12 = prm[6], T21 = prm[7], T22 = prm[8];
    float e1 = 0.f, e2 = 0.f;
    float* base = ws + OFF_SUM + (size_t)b * 65536 + ch * 2;
#pragma unroll 8
    for (int j = 0; j < NC_; ++j) {
        float2 l = *(float2*)(base + (size_t)j * 512);
        *(float2*)(base + (size_t)j * 512) = make_float2(e1, e2);
        float n1 = fmaf(T11, e1, fmaf(T12, e2, l.x));
        float n2 = fmaf(T21, e1, fmaf(T22, e2, l.y));
        e1 = n1; e2 = n2;
    }
}

// ---------------------------------------------------------------------------
// Fused 2: recompute GEMM1 (bitwise identical, fp32 tile) + replay scan with
// prefix (fp32 reads), write bf16 ys into a SEPARATE LDS region (round-2
// proven layout — no aliasing with fl), then GEMM2 + D.*x epilogue.
// grid = 1024 x 256.  LDS = 66560 + 33792 = 100352 B -> 1 blk/CU
// ---------------------------------------------------------------------------
__global__ __launch_bounds__(256) void k_fuse2(const float* __restrict__ X,
                                               const float* __restrict__ Dv,
                                               float* __restrict__ ws,
                                               float* __restrict__ out)
{
    __shared__ __align__(16) char smem[64 * 260 * 4];
    unsigned short (*xs)[136] = (unsigned short (*)[136])smem;  // alias (dead after GEMM1)
    float (*fl)[260]          = (float (*)[260])smem;           // fp32 F tile
    __shared__ __align__(16) unsigned short ysb[64][264];       // bf16 ys (separate!)

    int tid = threadIdx.x;
    int b = blockIdx.x >> 7, c = blockIdx.x & 127;
    size_t row0 = (size_t)b * LEN_ + (size_t)c * CT_;

    stage_x(X, row0, tid, xs);
    __syncthreads();

    int wv = tid >> 6, lane = tid & 63;
    int l15 = lane & 15, quad = lane >> 4, nbase = wv * 64;
    {
        f32x4 acc[4][4] = {};
        gemm1_acc(xs, (const unsigned short*)(ws + OFF_W1T), wv, lane, acc);
        __syncthreads();        // xs fully consumed; fl may now overwrite it
#pragma unroll
        for (int mi = 0; mi < 4; ++mi)
#pragma unroll
            for (int nj = 0; nj < 4; ++nj)
#pragma unroll
                for (int r = 0; r < 4; ++r)
                    fl[mi * 16 + quad * 4 + r][nbase + nj * 16 + l15] = acc[mi][nj][r];
    }
    __syncthreads();

    // replay scan with prefix: fp32 u from fl, bf16 ys -> ysb (disjoint region)
    {
        const float* prm = ws + OFF_PRM + (tid >> 1) * 16;
        float M11 = prm[0], M12 = prm[1], M21 = prm[2], M22 = prm[3], dts = prm[4];
        float2 s = *(const float2*)(ws + OFF_SUM + (((size_t)b * NC_ + c) * 256 + tid) * 2);
        float h1 = s.x, h2 = s.y;
#pragma unroll 8
        for (int t = 0; t < CT_; ++t) {
            float u = fl[t][tid];
            float n1 = fmaf(M11, h1, fmaf(M12, h2, u));
            float n2 = fmaf(M21, h1, fmaf(M22, h2, dts * u));
            h1 = n1; h2 = n2;
            ysb[t][tid] = f2bf(h2);
        }
    }
    __syncthreads();

    // GEMM2 64x128x256: A = ys (LDS bf16), B-frags from global W2T (L2-hot)
    int mrow = (wv & 1) * 32, ncol = (wv >> 1) * 64;
    f32x4 a2[2][4] = {};
    const unsigned short* W2T = (const unsigned short*)(ws + OFF_W2T);
#pragma unroll
    for (int kk = 0; kk < 8; ++kk) {
        int k0 = kk * 32 + quad * 8;
        bf16x8 af[2], bg[4];
#pragma unroll
        for (int mi = 0; mi < 2; ++mi) af[mi] = *(const bf16x8*)&ysb[mrow + mi * 16 + l15][k0];
#pragma unroll
        for (int nj = 0; nj < 4; ++nj)
            bg[nj] = *(const bf16x8*)(W2T + (size_t)(ncol + nj * 16 + l15) * 256 + k0);
#pragma unroll
        for (int mi = 0; mi < 2; ++mi)
#pragma unroll
            for (int nj = 0; nj < 4; ++nj)
                a2[mi][nj] = __builtin_amdgcn_mfma_f32_16x16x32_bf16(af[mi], bg[nj], a2[mi][nj], 0, 0, 0);
    }

    // epilogue: out = a2 + D .* x (fp32 exact)
#pragma unroll
    for (int mi = 0; mi < 2; ++mi)
#pragma unroll
        for (int nj = 0; nj < 4; ++nj) {
            int col = ncol + nj * 16 + l15;
            float d = Dv[col];
#pragma unroll
            for (int r = 0; r < 4; ++r) {
                size_t gr = row0 + mrow + mi * 16 + quad * 4 + r;
                float xv = X[gr * 128 + col];
                out[gr * 128 + col] = fmaf(d, xv, a2[mi][nj][r]);
            }
        }
}

// ---------------------------------------------------------------------------
extern "C" void kernel_launch(void* const* d_in, const int* in_sizes, int n_in,
                              void* d_out, int out_size, void* d_ws, size_t ws_size,
                              hipStream_t stream) {
    const float* x      = (const float*)d_in[0];
    const float* A_diag = (const float*)d_in[1];
    const float* G_diag = (const float*)d_in[2];
    const float* dt     = (const float*)d_in[3];
    const float* B      = (const float*)d_in[4];
    const float* C      = (const float*)d_in[5];
    const float* Dv     = (const float*)d_in[6];
    float* out = (float*)d_out;
    float* ws  = (float*)d_ws;

    k_setup<<<128, 256, 0, stream>>>(A_diag, G_diag, dt, B, C, ws);
    k_fuse1<<<BSZ_ * NC_, 256, 0, stream>>>(x, ws);
    k_scan2<<<32, 64, 0, stream>>>(ws);
    k_fuse2<<<BSZ_ * NC_, 256, 0, stream>>>(x, Dv, ws, out);
}

// Round 7
// 148.111 us; speedup vs baseline: 1.8430x; 1.0229x over previous
//
#include <hip/hip_runtime.h>
#include <math.h>

// Problem dims
#define BSZ_ 8
#define LEN_ 8192
#define NC_  128          // scan chunks per sequence
#define CT_  64           // chunk length

typedef __attribute__((ext_vector_type(8))) short bf16x8;
typedef __attribute__((ext_vector_type(4))) float f32x4;

// Workspace layout (float offsets).  Total ~69.4 MB
#define OFF_PRM 0                                   // 128*16 per-p scalars
#define OFF_W1T 2048                                // bf16 [256][128]  (W1^T: [pc][h])
#define OFF_W2T (OFF_W1T + 16384)                   // bf16 [128][256]  (W2^T: [h][pc])
#define OFF_MPW (OFF_W2T + 16384)                   // float2 [65][128]: (m21,m22) of M^k, k-major
#define OFF_SUM (OFF_MPW + 16640)                   // f32 chunk summaries/prefixes [8][128][256][2]
#define OFF_V2  (OFF_SUM + BSZ_*NC_*256*2)          // f32 v2 (chunk-local y) [8][8192][256]

__device__ __forceinline__ unsigned short f2bf(float f) {
    unsigned u = __builtin_bit_cast(unsigned, f);
    u += 0x7fffu + ((u >> 16) & 1u);               // round-to-nearest-even
    return (unsigned short)(u >> 16);
}

// ---------------------------------------------------------------------------
// Setup: parallel weight conversion + per-p scalars + M-power table (k-major)
// grid = 128 x 256
// ---------------------------------------------------------------------------
__global__ __launch_bounds__(256) void k_setup(const float* __restrict__ A_diag,
                                               const float* __restrict__ G_diag,
                                               const float* __restrict__ dt,
                                               const float* __restrict__ B,
                                               const float* __restrict__ C,
                                               float* __restrict__ ws)
{
    int i = blockIdx.x * 256 + threadIdx.x;        // 0..32767
    // W1T[pc][h] = c1[p] * B[p,h,c]
    {
        int pc = i >> 7, h = i & 127;
        int p = pc >> 1, cc = pc & 1;
        float dts = 1.f / (1.f + expf(-dt[p]));
        float G = fmaxf(G_diag[p], 0.f);
        float c1 = dts / (1.f + dts * G);
        ((unsigned short*)(ws + OFF_W1T))[i] = f2bf(c1 * B[p * 256 + h * 2 + cc]);
    }
    // W2T[h][pc] = +Cr / -Ci ; C layout is exactly linear in i
    {
        float v = C[i];
        ((unsigned short*)(ws + OFF_W2T))[i] = f2bf((i & 1) ? -v : v);
    }
    if (blockIdx.x == 0 && threadIdx.x < 128) {
        int p = threadIdx.x;
        float dtv = dt[p];
        float dts = 1.f / (1.f + expf(-dtv));
        float A   = fmaxf(A_diag[p], 0.f);
        float G   = fmaxf(G_diag[p], 0.f);
        float dt2 = fmaxf(dts * dts, 1e-6f);
        float s   = sqrtf(1.f + dts * G);
        float A_low  = (2.f + dts * G - 2.f * s) / dt2;
        float A_high = (2.f + dts * G + 2.f * s) / dt2;
        float Af = A_low + fmaxf(A - A_low, 0.f) - fmaxf(A - A_high, 0.f);
        float S   = 1.f + dts * G;
        float M11 = 1.f / S;
        float M12 = -(dts / S) * Af;
        float M21 = dts / S;
        float M22 = 1.f - (dts * dts / S) * Af;
        // M^64 via 6 squarings (for scan2)
        float t11 = M11, t12 = M12, t21 = M21, t22 = M22;
#pragma unroll
        for (int it = 0; it < 6; ++it) {
            float n11 = t11 * t11 + t12 * t21;
            float n12 = t11 * t12 + t12 * t22;
            float n21 = t21 * t11 + t22 * t21;
            float n22 = t21 * t12 + t22 * t22;
            t11 = n11; t12 = n12; t21 = n21; t22 = n22;
        }
        float* prm = ws + OFF_PRM + p * 16;
        prm[0] = M11; prm[1] = M12; prm[2] = M21; prm[3] = M22; prm[4] = dts;
        prm[5] = t11; prm[6] = t12; prm[7] = t21; prm[8] = t22;

        // M-power table: MPW[k][p] = (m21, m22) of M^k, k = 1..64 (k-major for
        // coalesced reads in k_fuse2)
        float2* MPW = (float2*)(ws + OFF_MPW);
        float c11 = M11, c12 = M12, c21 = M21, c22 = M22;
        for (int k = 1; k <= 64; ++k) {
            MPW[k * 128 + p] = make_float2(c21, c22);
            float n11 = M11 * c11 + M12 * c21;
            float n12 = M11 * c12 + M12 * c22;
            float n21 = M21 * c11 + M22 * c21;
            float n22 = M21 * c12 + M22 * c22;
            c11 = n11; c12 = n12; c21 = n21; c22 = n22;
        }
    }
}

// ---------------------------------------------------------------------------
// Shared device pieces
// ---------------------------------------------------------------------------
__device__ __forceinline__ void stage_x(const float* __restrict__ X, size_t row0,
                                        int tid, unsigned short (*xs)[136])
{
    int r = tid >> 4, cl = (tid & 15) * 8;
#pragma unroll
    for (int i = 0; i < 4; ++i) {
        int rr = r + i * 16;
        const float* src = X + (row0 + rr) * 128 + cl;
        float4 v0 = *(const float4*)src;
        float4 v1 = *(const float4*)(src + 4);
        unsigned short* dst = &xs[rr][cl];
        dst[0] = f2bf(v0.x); dst[1] = f2bf(v0.y); dst[2] = f2bf(v0.z); dst[3] = f2bf(v0.w);
        dst[4] = f2bf(v1.x); dst[5] = f2bf(v1.y); dst[6] = f2bf(v1.z); dst[7] = f2bf(v1.w);
    }
}

// GEMM1 64x256x128: A = xs (LDS), B-frags straight from global W1T (L2-hot)
__device__ __forceinline__ void gemm1_acc(const unsigned short (*xs)[136],
                                          const unsigned short* __restrict__ W1T,
                                          int wv, int lane, f32x4 acc[4][4])
{
    int l15 = lane & 15, quad = lane >> 4;
    int nbase = wv * 64;
#pragma unroll
    for (int kk = 0; kk < 4; ++kk) {
        int k0 = kk * 32 + quad * 8;
        bf16x8 af[4], bg[4];
#pragma unroll
        for (int mi = 0; mi < 4; ++mi) af[mi] = *(const bf16x8*)&xs[mi * 16 + l15][k0];
#pragma unroll
        for (int nj = 0; nj < 4; ++nj)
            bg[nj] = *(const bf16x8*)(W1T + (size_t)(nbase + nj * 16 + l15) * 128 + k0);
#pragma unroll
        for (int mi = 0; mi < 4; ++mi)
#pragma unroll
            for (int nj = 0; nj < 4; ++nj)
                acc[mi][nj] = __builtin_amdgcn_mfma_f32_16x16x32_bf16(af[mi], bg[nj], acc[mi][nj], 0, 0, 0);
    }
}

// ---------------------------------------------------------------------------
// Fused 1: GEMM1 + chunk-local scan (fp32, zero init) in TWO 32-row halves
// through a 32-row fl buffer aliased over xs.  Writes v2 (=local y) fp32 to
// global + chunk summary.  LDS = 32*260*4 = 33.3 KB -> ~4 blk/CU
// grid = 1024 x 256
// ---------------------------------------------------------------------------
__global__ __launch_bounds__(256) void k_fuse1(const float* __restrict__ X,
                                               float* __restrict__ ws)
{
    __shared__ __align__(16) char smem[32 * 260 * 4];
    unsigned short (*xs)[136] = (unsigned short (*)[136])smem;  // alias (dead after GEMM1)
    float (*fl)[260] = (float (*)[260])smem;                    // fp32 half-tile (32 rows)

    int tid = threadIdx.x;
    int b = blockIdx.x >> 7, c = blockIdx.x & 127;
    size_t row0 = (size_t)b * LEN_ + (size_t)c * CT_;

    stage_x(X, row0, tid, xs);
    __syncthreads();

    int wv = tid >> 6, lane = tid & 63;
    int l15 = lane & 15, quad = lane >> 4, nbase = wv * 64;
    f32x4 acc[4][4] = {};
    gemm1_acc(xs, (const unsigned short*)(ws + OFF_W1T), wv, lane, acc);
    __syncthreads();            // xs fully consumed; fl may now overwrite it

    const float* prm = ws + OFF_PRM + (tid >> 1) * 16;
    float M11 = prm[0], M12 = prm[1], M21 = prm[2], M22 = prm[3], dts = prm[4];
    float* V2 = ws + OFF_V2;
    float h1 = 0.f, h2 = 0.f;

#pragma unroll
    for (int half = 0; half < 2; ++half) {
        // stage rows [half*32, half*32+32) of acc into fl
#pragma unroll
        for (int mi = 0; mi < 2; ++mi)
#pragma unroll
            for (int nj = 0; nj < 4; ++nj)
#pragma unroll
                for (int r = 0; r < 4; ++r)
                    fl[mi * 16 + quad * 4 + r][nbase + nj * 16 + l15] =
                        acc[half * 2 + mi][nj][r];
        __syncthreads();
        // scan 32 rows (state carries across halves in registers)
#pragma unroll 8
        for (int t = 0; t < 32; ++t) {
            float u = fl[t][tid];
            float n1 = fmaf(M11, h1, fmaf(M12, h2, u));
            float n2 = fmaf(M21, h1, fmaf(M22, h2, dts * u));
            h1 = n1; h2 = n2;
            V2[(row0 + half * 32 + t) * 256 + tid] = h2;   // fp32 local y
        }
        __syncthreads();        // fl reads done before next half overwrites
    }
    *(float2*)(ws + OFF_SUM + (((size_t)b * NC_ + c) * 256 + tid) * 2) = make_float2(h1, h2);
}

// ---------------------------------------------------------------------------
// Pass 2: sequential combine of chunk summaries -> exclusive prefixes.
// grid = 32 x 64
// ---------------------------------------------------------------------------
__global__ __launch_bounds__(64) void k_scan2(float* __restrict__ ws)
{
    int b = blockIdx.x >> 2, cg = blockIdx.x & 3;
    int ch = cg * 64 + threadIdx.x;
    const float* prm = ws + OFF_PRM + (ch >> 1) * 16;
    float T11 = prm[5], T12 = prm[6], T21 = prm[7], T22 = prm[8];
    float e1 = 0.f, e2 = 0.f;
    float* base = ws + OFF_SUM + (size_t)b * 65536 + ch * 2;
#pragma unroll 8
    for (int j = 0; j < NC_; ++j) {
        float2 l = *(float2*)(base + (size_t)j * 512);
        *(float2*)(base + (size_t)j * 512) = make_float2(e1, e2);
        float n1 = fmaf(T11, e1, fmaf(T12, e2, l.x));
        float n2 = fmaf(T21, e1, fmaf(T22, e2, l.y));
        e1 = n1; e2 = n2;
    }
}

// ---------------------------------------------------------------------------
// Fused 2: ys_t = v2_t + [M^{t+1} C]_2  (v2 fp32 from global, C = chunk
// prefix fp32, M-powers fp32 from table) -> ysb LDS bf16 -> GEMM2 + D.*x.
// No GEMM1 recompute, no serial scan.  LDS = 33.8 KB -> 4 blk/CU
// grid = 1024 x 256
// ---------------------------------------------------------------------------
__global__ __launch_bounds__(256) void k_fuse2(const float* __restrict__ X,
                                               const float* __restrict__ Dv,
                                               float* __restrict__ ws,
                                               float* __restrict__ out)
{
    __shared__ __align__(16) unsigned short ysb[64][264];

    int tid = threadIdx.x;
    int b = blockIdx.x >> 7, c = blockIdx.x & 127;
    size_t row0 = (size_t)b * LEN_ + (size_t)c * CT_;

    // ---- build ys tile: channel = tid ----
    {
        int p = tid >> 1;
        float2 C = *(const float2*)(ws + OFF_SUM + (((size_t)b * NC_ + c) * 256 + tid) * 2);
        const float2* MPW = (const float2*)(ws + OFF_MPW);
        const float* V2 = ws + OFF_V2 + row0 * 256 + tid;
#pragma unroll 8
        for (int t = 0; t < 64; ++t) {
            float v2 = V2[(size_t)t * 256];
            float2 m = MPW[(t + 1) * 128 + p];             // (m21, m22) of M^{t+1}
            float y = fmaf(m.x, C.x, fmaf(m.y, C.y, v2));
            ysb[t][tid] = f2bf(y);
        }
    }
    __syncthreads();

    // ---- GEMM2 64x128x256: A = ys (LDS bf16), B-frags from global W2T ----
    int wv = tid >> 6, lane = tid & 63;
    int l15 = lane & 15, quad = lane >> 4;
    int mrow = (wv & 1) * 32, ncol = (wv >> 1) * 64;
    f32x4 a2[2][4] = {};
    const unsigned short* W2T = (const unsigned short*)(ws + OFF_W2T);
#pragma unroll
    for (int kk = 0; kk < 8; ++kk) {
        int k0 = kk * 32 + quad * 8;
        bf16x8 af[2], bg[4];
#pragma unroll
        for (int mi = 0; mi < 2; ++mi) af[mi] = *(const bf16x8*)&ysb[mrow + mi * 16 + l15][k0];
#pragma unroll
        for (int nj = 0; nj < 4; ++nj)
            bg[nj] = *(const bf16x8*)(W2T + (size_t)(ncol + nj * 16 + l15) * 256 + k0);
#pragma unroll
        for (int mi = 0; mi < 2; ++mi)
#pragma unroll
            for (int nj = 0; nj < 4; ++nj)
                a2[mi][nj] = __builtin_amdgcn_mfma_f32_16x16x32_bf16(af[mi], bg[nj], a2[mi][nj], 0, 0, 0);
    }

    // ---- epilogue: out = a2 + D .* x (fp32 exact) ----
#pragma unroll
    for (int mi = 0; mi < 2; ++mi)
#pragma unroll
        for (int nj = 0; nj < 4; ++nj) {
            int col = ncol + nj * 16 + l15;
            float d = Dv[col];
#pragma unroll
            for (int r = 0; r < 4; ++r) {
                size_t gr = row0 + mrow + mi * 16 + quad * 4 + r;
                float xv = X[gr * 128 + col];
                out[gr * 128 + col] = fmaf(d, xv, a2[mi][nj][r]);
            }
        }
}

// ---------------------------------------------------------------------------
extern "C" void kernel_launch(void* const* d_in, const int* in_sizes, int n_in,
                              void* d_out, int out_size, void* d_ws, size_t ws_size,
                              hipStream_t stream) {
    const float* x      = (const float*)d_in[0];
    const float* A_diag = (const float*)d_in[1];
    const float* G_diag = (const float*)d_in[2];
    const float* dt     = (const float*)d_in[3];
    const float* B      = (const float*)d_in[4];
    const float* C      = (const float*)d_in[5];
    const float* Dv     = (const float*)d_in[6];
    float* out = (float*)d_out;
    float* ws  = (float*)d_ws;

    k_setup<<<128, 256, 0, stream>>>(A_diag, G_diag, dt, B, C, ws);
    k_fuse1<<<BSZ_ * NC_, 256, 0, stream>>>(x, ws);
    k_scan2<<<32, 64, 0, stream>>>(ws);
    k_fuse2<<<BSZ_ * NC_, 256, 0, stream>>>(x, Dv, ws, out);
}